// Round 17
// baseline (97.195 us; speedup 1.0000x reference)
//
#include <hip/hip_runtime.h>

typedef __fp16 h2v __attribute__((ext_vector_type(2)));
typedef _Float16 f16x8 __attribute__((ext_vector_type(8)));
typedef float f32x4 __attribute__((ext_vector_type(4)));

#define BLK 256
#define BATCH 8192

// ================= GF(2) 12x12 compile-time machinery =================
struct M12 { unsigned r[12]; };

constexpr M12 mp_matrix() {
  // CNOT-ring permutation y = P x (verified rounds 1-16)
  M12 m{};
  for (int p = 0; p <= 10; ++p) m.r[p] = (0xFFFu >> p) << p;
  m.r[11] = 0x7FFu;
  return m;
}
constexpr M12 MP = mp_matrix();

constexpr unsigned mv(const M12 m, unsigned v) {
  unsigned y = 0;
  for (int p = 0; p < 12; ++p)
    y |= (unsigned)(__builtin_popcount(m.r[p] & v) & 1) << p;
  return y;
}
constexpr M12 mmul(const M12 a, const M12 b) {     // c(x) = a(b(x))
  M12 c{};
  for (int p = 0; p < 12; ++p) {
    unsigned acc = 0;
    for (int q = 0; q < 12; ++q)
      if ((a.r[p] >> q) & 1u) acc ^= b.r[q];
    c.r[p] = acc;
  }
  return c;
}
constexpr M12 minv(const M12 a0) {
  unsigned a[12] = {}, v[12] = {};
  for (int i = 0; i < 12; ++i) { a[i] = a0.r[i]; v[i] = 1u << i; }
  for (int c = 0; c < 12; ++c) {
    int piv = c;
    while (!((a[piv] >> c) & 1u)) ++piv;   // OOB => constexpr error (singular)
    unsigned ta = a[piv], tv = v[piv];
    a[piv] = a[c]; v[piv] = v[c]; a[c] = ta; v[c] = tv;
    for (int r2 = 0; r2 < 12; ++r2)
      if (r2 != c && ((a[r2] >> c) & 1u)) { a[r2] ^= a[c]; v[r2] ^= v[c]; }
  }
  M12 out{};
  for (int i = 0; i < 12; ++i) out.r[i] = v[i];
  return out;
}
constexpr unsigned colq(const M12 m, int q) {
  unsigned c = 0;
  for (int p = 0; p < 12; ++p) c |= ((m.r[p] >> q) & 1u) << p;
  return c;
}
constexpr M12 from_cols(const unsigned (&c)[12]) {
  M12 m{};
  for (int p = 0; p < 12; ++p) {
    unsigned row = 0;
    for (int j = 0; j < 12; ++j) row |= ((c[j] >> p) & 1u) << j;
    m.r[p] = row;
  }
  return m;
}
constexpr M12 mk_id() { M12 m{}; for (int p = 0; p < 12; ++p) m.r[p] = 1u << p; return m; }
constexpr M12 MID = mk_id();
constexpr M12 MPI = minv(MP);

constexpr bool meq(const M12 a, const M12 b) {
  for (int p = 0; p < 12; ++p) if (a.r[p] != b.r[p]) return false;
  return true;
}
static_assert(meq(mmul(MP, MPI), MID), "P inverse");

struct Frame { M12 A, Ai; };
constexpr Frame FID{MID, MID};
constexpr Frame absorb(const Frame f) { return Frame{ mmul(MP, f.A), mmul(f.Ai, MPI) }; }
constexpr Frame apply_tau(const Frame f, const M12 t) {
  return Frame{ mmul(f.A, minv(t)), mmul(t, f.Ai) };
}

// ---- completion search (sources + null-space completion) ----
struct SSet { unsigned S[12]; };

constexpr int rank_msk(const unsigned* v, int n, unsigned msk) {
  unsigned basis[5] = {};
  int r = 0;
  for (int i = 0; i < n; ++i) {
    unsigned x = v[i] & msk;
    for (int b = 4; b >= 0; --b) {
      if (!((x >> b) & 1u)) continue;
      if (basis[b]) x ^= basis[b];
      else { basis[b] = x; ++r; break; }
    }
  }
  return r;
}
constexpr int rank_hi(const unsigned* v, int n) {   // rank of bits [11:5]
  unsigned basis[7] = {};
  int r = 0;
  for (int i = 0; i < n; ++i) {
    unsigned x = (v[i] >> 5) & 127u;
    for (int b = 6; b >= 0; --b) {
      if (!((x >> b) & 1u)) continue;
      if (basis[b]) x ^= basis[b];
      else { basis[b] = x; ++r; break; }
    }
  }
  return r;
}
constexpr bool ins_ech(unsigned (&e)[12], unsigned x) {
  for (int b = 11; b >= 0; --b) {
    if (!((x >> b) & 1u)) continue;
    if (e[b]) x ^= e[b];
    else { e[b] = x; return true; }
  }
  return false;
}
// Greedy: S[4..7] maximize (1) bank bits [1:0] diversity (B can't touch),
// (2) high-part [11:5] rank (gives B full injection freedom), (3) bank rank.
constexpr SSet build_S(const Frame f, const int* qs) {
  SSet s{};
  unsigned rows[4] = {};
  for (int i = 0; i < 4; ++i) {
    s.S[i] = colq(f.Ai, qs[i]);
    rows[i] = f.A.r[qs[i]];
  }
  unsigned R[4] = {rows[0], rows[1], rows[2], rows[3]};
  int pivcol[4] = {-1, -1, -1, -1};
  int nr = 0;
  for (int cc = 0; cc < 12 && nr < 4; ++cc) {
    int pr = -1;
    for (int r2 = nr; r2 < 4; ++r2) if ((R[r2] >> cc) & 1u) { pr = r2; break; }
    if (pr < 0) continue;
    unsigned tmp = R[nr]; R[nr] = R[pr]; R[pr] = tmp;
    for (int r2 = 0; r2 < 4; ++r2)
      if (r2 != nr && ((R[r2] >> cc) & 1u)) R[r2] ^= R[nr];
    pivcol[nr] = cc; ++nr;
  }
  unsigned nb[8] = {};
  int nc = 0;
  for (int j = 0; j < 12; ++j) {
    bool isp = false;
    for (int k = 0; k < nr; ++k) if (pivcol[k] == j) isp = true;
    if (isp) continue;
    unsigned v = 1u << j;
    for (int k = 0; k < nr; ++k) if ((R[k] >> j) & 1u) v |= 1u << pivcol[k];
    nb[nc] = v;
    ++nc;
  }
  unsigned pool[36] = {};
  int np = 0;
  for (int j = 0; j < 8; ++j) pool[np++] = nb[j];
  for (int j = 0; j < 8; ++j)
    for (int k = j + 1; k < 8; ++k) pool[np++] = nb[j] ^ nb[k];
  unsigned ech[12] = {};
  unsigned readset[5] = {};
  int nrs = 0;
  readset[nrs++] = s.S[0];
  for (int slot = 4; slot <= 7; ++slot) {
    int best = -1;
    unsigned bestc = 0;
    for (int c = 0; c < np; ++c) {
      unsigned tmp[12];
      for (int z = 0; z < 12; ++z) tmp[z] = ech[z];
      if (!ins_ech(tmp, pool[c])) continue;
      readset[nrs] = pool[c];
      const int score = rank_msk(readset, nrs + 1, 3u) * 128 +
                        rank_hi(readset, nrs + 1) * 16 +
                        rank_msk(readset, nrs + 1, 31u);
      if (score > best) { best = score; bestc = pool[c]; }
    }
    s.S[slot] = bestc;
    ins_ech(ech, bestc);
    readset[nrs++] = bestc;
  }
  const int rem[4] = {8, 9, 10, 11};
  for (int t = 0; t < 4; ++t) {
    for (int c = 0; c < np; ++c) {
      unsigned tmp[12];
      for (int z = 0; z < 12; ++z) tmp[z] = ech[z];
      if (!ins_ech(tmp, pool[c])) continue;
      s.S[rem[t]] = pool[c];
      ins_ech(ech, pool[c]);
      break;
    }
  }
  return s;
}
constexpr unsigned T4[4] = {8u, 4u, 2u, 1u};
constexpr M12 tau_of(const SSet s) {
  unsigned Sc[12], Dc[12];
  for (int i = 0; i < 12; ++i) {
    Sc[i] = s.S[i];
    Dc[i] = (i < 4) ? T4[i] : (1u << i);
  }
  return mmul(from_cols(Dc), minv(from_cols(Sc)));
}
constexpr bool chk_group(const Frame f, const int* qs) {
  for (int i = 0; i < 4; ++i) if (colq(f.Ai, qs[i]) != T4[i]) return false;
  return true;
}

// ---- B swizzle: layout bijection keyed on addr bits [11:5], injecting into
// bank bits [4:2]; identity on [1:0].  EXACT SOLVE: f(high) is a free linear
// map, so per-vector injections are constructible wherever high parts are
// independent -> target bank-rank 5 (conflict-free scatter reads).
struct BSw { unsigned mk[7]; };
constexpr unsigned bapp(const BSw& b, unsigned v) {
  unsigned o = v;
  for (int k = 0; k < 7; ++k)
    if ((v >> (5 + k)) & 1u) o ^= b.mk[k];
  return o;
}
constexpr int brank_read(const BSw& b, const SSet& s) {
  unsigned v[5] = { bapp(b, s.S[0]), bapp(b, s.S[4]), bapp(b, s.S[5]),
                    bapp(b, s.S[6]), bapp(b, s.S[7]) };
  return rank_msk(v, 5, 31u);
}
constexpr BSw find_B(const SSet& s) {
  const unsigned v[5] = { s.S[0], s.S[4], s.S[5], s.S[6], s.S[7] };
  unsigned bh[7] = {};   // echelon basis of high parts (leading-bit indexed)
  unsigned bd[7] = {};   // assigned 3-bit injection values
  unsigned w[5] = {};    // resulting bank images
  for (int i = 0; i < 5; ++i) {
    unsigned h = (v[i] >> 5) & 127u, dacc = 0u;
    for (int b = 6; b >= 0; --b)
      if (((h >> b) & 1u) && bh[b]) { h ^= bh[b]; dacc ^= bd[b]; }
    const unsigned base = v[i] & 31u;
    if (h != 0u) {
      // free vector: choose injection d maximizing incremental bank rank
      int bestrk = -1;
      unsigned bestd = 0;
      for (unsigned d = 0; d < 8; ++d) {
        w[i] = base ^ (d << 2);
        const int rk = rank_msk(w, i + 1, 31u);
        if (rk > bestrk) { bestrk = rk; bestd = d; }
      }
      w[i] = base ^ (bestd << 2);
      int lead = 6;
      while (!((h >> lead) & 1u)) --lead;
      bh[lead] = h;
      bd[lead] = bestd ^ dacc;     // f(residual) so that f(v_high) = bestd
    } else {
      w[i] = base ^ (dacc << 2);   // dependent: injection forced
    }
  }
  // mk[k] = f(e_k) by reduction (extend by zero outside constraint span)
  BSw b{};
  for (int k = 0; k < 7; ++k) {
    unsigned h = 1u << k, dacc = 0u;
    for (int bb = 6; bb >= 0; --bb)
      if (((h >> bb) & 1u) && bh[bb]) { h ^= bh[bb]; dacc ^= bd[bb]; }
    if (h != 0u) {
      int lead = 6;
      while (!((h >> lead) & 1u)) --lead;
      bh[lead] = h;
      bd[lead] = 0u;
    }
    b.mk[k] = dacc << 2;
  }
  return b;
}

constexpr int QA[4] = {11, 10, 9, 8};
constexpr int QB[4] = {7, 6, 5, 4};
constexpr int QC[4] = {3, 2, 1, 0};

constexpr Frame F1  = absorb(FID);
constexpr SSet C0 = build_S(F1, QA);
constexpr M12  T0 = tau_of(C0);
constexpr Frame F2a = apply_tau(F1, T0);
constexpr SSet C1 = build_S(F2a, QB);
constexpr M12  T1 = tau_of(C1);
constexpr Frame F2b = apply_tau(F2a, T1);
constexpr SSet C2 = build_S(F2b, QC);
constexpr M12  T2 = tau_of(C2);
constexpr Frame F2c = apply_tau(F2b, T2);
constexpr Frame F3  = absorb(F2c);
constexpr SSet C3 = build_S(F3, QA);
constexpr M12  T3m = tau_of(C3);
constexpr Frame F3a = apply_tau(F3, T3m);
constexpr SSet C4 = build_S(F3a, QB);
constexpr M12  T4m = tau_of(C4);
constexpr Frame F3b = apply_tau(F3a, T4m);
constexpr SSet C5 = build_S(F3b, QC);
constexpr M12  T5m = tau_of(C5);
constexpr Frame F3c = apply_tau(F3b, T5m);
constexpr Frame F4  = absorb(F3c);

static_assert(chk_group(F2a, QA), "G2a");
static_assert(chk_group(F2b, QB), "G2b");
static_assert(chk_group(F2c, QC), "G2c");
static_assert(chk_group(F3a, QA), "G3a");
static_assert(chk_group(F3b, QB), "G3b");
static_assert(chk_group(F3c, QC), "G3c");
static_assert(F2a.A.r[11] == 8u && F2a.A.r[10] == 4u && F2a.A.r[9] == 2u && F2a.A.r[8] == 1u, "rows2a");
static_assert(F2b.A.r[7]  == 8u && F2b.A.r[6]  == 4u && F2b.A.r[5] == 2u && F2b.A.r[4] == 1u, "rows2b");
static_assert(F2c.A.r[3]  == 8u && F2c.A.r[2]  == 4u && F2c.A.r[1] == 2u && F2c.A.r[0] == 1u, "rows2c");
static_assert(F3a.A.r[11] == 8u && F3a.A.r[10] == 4u && F3a.A.r[9] == 2u && F3a.A.r[8] == 1u, "rows3a");
static_assert(F3b.A.r[7]  == 8u && F3b.A.r[6]  == 4u && F3b.A.r[5] == 2u && F3b.A.r[4] == 1u, "rows3b");
static_assert(F3c.A.r[3]  == 8u && F3c.A.r[2]  == 4u && F3c.A.r[1] == 2u && F3c.A.r[0] == 1u, "rows3c");

constexpr BSw B0 = find_B(C0);
constexpr BSw B1 = find_B(C1);
constexpr BSw B2 = find_B(C2);
constexpr BSw B3 = find_B(C3);
constexpr BSw B4 = find_B(C4);
constexpr BSw B5 = find_B(C5);
static_assert(brank_read(B0, C0) >= 3 && brank_read(B1, C1) >= 3 &&
              brank_read(B2, C2) >= 3 && brank_read(B3, C3) >= 3 &&
              brank_read(B4, C4) >= 3 && brank_read(B5, C5) >= 3, "rr");

// per-pass tables: read side (reads scatter via B(tau^-1)), write side
// (linear D-positions mapped through the same B)
struct PT {
  unsigned rlb[5]; unsigned rwb[2]; unsigned ro[32];
  unsigned wlb[4]; unsigned wm[2]; unsigned wwb[2];
};
constexpr PT mk_pt(const SSet s, const BSw b) {
  PT t{};
  t.rlb[0] = bapp(b, s.S[4]); t.rlb[1] = bapp(b, s.S[5]);
  t.rlb[2] = bapp(b, s.S[6]); t.rlb[3] = bapp(b, s.S[7]);
  t.rlb[4] = bapp(b, s.S[0]);
  t.rwb[0] = bapp(b, s.S[10]); t.rwb[1] = bapp(b, s.S[11]);
  for (int m = 0; m < 4; ++m)
    for (int j = 0; j < 8; ++j)
      t.ro[(m << 3) | j] = bapp(b,
          ((m & 1) ? s.S[8] : 0u) ^ ((m & 2) ? s.S[9] : 0u) ^
          ((j & 1) ? s.S[3] : 0u) ^ ((j & 2) ? s.S[2] : 0u) ^
          ((j & 4) ? s.S[1] : 0u));
  for (int k = 0; k < 4; ++k) t.wlb[k] = bapp(b, 1u << (4 + k));
  t.wm[0] = bapp(b, 256u);  t.wm[1] = bapp(b, 512u);
  t.wwb[0] = bapp(b, 1024u); t.wwb[1] = bapp(b, 2048u);
  return t;
}
constexpr PT RT[6] = { mk_pt(C0, B0), mk_pt(C1, B1), mk_pt(C2, B2),
                       mk_pt(C3, B3), mk_pt(C4, B4), mk_pt(C5, B5) };

// ================= device helpers =================
template<int PI>
__device__ __forceinline__ unsigned rbase_of(const int lane, const int w) {
  unsigned rb = 0u;
  #pragma unroll
  for (int k = 0; k < 4; ++k) rb ^= ((lane >> k) & 1) ? RT[PI].rlb[k] : 0u;
  rb ^= ((lane >> 4) & 1) ? RT[PI].rlb[4] : 0u;
  rb ^= (w & 1) ? RT[PI].rwb[0] : 0u;
  rb ^= (w & 2) ? RT[PI].rwb[1] : 0u;
  return rb;
}

// scatter-read B-fragments (half-wave partners read identical addresses ->
// LDS broadcast; sel extracts re/im plane) + MFMAs
template<int PI>
__device__ __forceinline__ void do_pass(f32x4 (&D1)[4], f32x4 (&D2)[4],
                                        const unsigned* sb,
                                        const uint4 a1u, const uint4 a2u,
                                        const int lane, const int w,
                                        const unsigned sel) {
  const f16x8 A1f = __builtin_bit_cast(f16x8, a1u);
  const f16x8 A2f = __builtin_bit_cast(f16x8, a2u);
  const unsigned rb = rbase_of<PI>(lane, w);
  const f32x4 z4 = {0.f, 0.f, 0.f, 0.f};
  #pragma unroll
  for (int m = 0; m < 4; ++m) {
    unsigned amp[8];
    #pragma unroll
    for (int j = 0; j < 8; ++j)
      amp[j] = sb[rb ^ RT[PI].ro[(m << 3) | j]];
    uint4 bw;
    bw.x = __builtin_amdgcn_perm(amp[1], amp[0], sel);
    bw.y = __builtin_amdgcn_perm(amp[3], amp[2], sel);
    bw.z = __builtin_amdgcn_perm(amp[5], amp[4], sel);
    bw.w = __builtin_amdgcn_perm(amp[7], amp[6], sel);
    const f16x8 Bf = __builtin_bit_cast(f16x8, bw);
    D1[m] = __builtin_amdgcn_mfma_f32_16x16x32_f16(A1f, Bf, z4, 0, 0, 0);
    D2[m] = __builtin_amdgcn_mfma_f32_16x16x32_f16(A2f, Bf, z4, 0, 0, 0);
  }
}

// b128 write of D-layout state at B(own position); PI = pass that READS this
// buffer (so writer and reader share the same B layout).
template<int PI>
__device__ __forceinline__ void write_state(const f32x4 (&D1)[4],
                                            const f32x4 (&D2)[4],
                                            unsigned* sb, const int lane,
                                            const int w) {
  unsigned wb = (unsigned)((lane >> 4) << 2);   // ks bits e2,e3 (B-identity)
  #pragma unroll
  for (int k = 0; k < 4; ++k) wb ^= ((lane >> k) & 1) ? RT[PI].wlb[k] : 0u;
  wb ^= (w & 1) ? RT[PI].wwb[0] : 0u;
  wb ^= (w & 2) ? RT[PI].wwb[1] : 0u;
  #pragma unroll
  for (int m = 0; m < 4; ++m) {
    const unsigned addr = wb ^ ((m & 1) ? RT[PI].wm[0] : 0u)
                             ^ ((m & 2) ? RT[PI].wm[1] : 0u);
    uint4 v;
    v.x = __builtin_bit_cast(unsigned, __builtin_amdgcn_cvt_pkrtz(D1[m][0], D2[m][0]));
    v.y = __builtin_bit_cast(unsigned, __builtin_amdgcn_cvt_pkrtz(D1[m][1], D2[m][1]));
    v.z = __builtin_bit_cast(unsigned, __builtin_amdgcn_cvt_pkrtz(D1[m][2], D2[m][2]));
    v.w = __builtin_bit_cast(unsigned, __builtin_amdgcn_cvt_pkrtz(D1[m][3], D2[m][3]));
    *(uint4*)(sb + addr) = v;
  }
}

// gate entry G=[[(gr,gi),(-hr,hi)],[(hr,hi),(gr,-gi)]], g=(gr,gi,hr,hi)
__device__ __forceinline__ void gentry(const float4 g, const int rb,
                                       const int kb, float& re, float& im) {
  re = rb ? (kb ? g.x : g.z) : (kb ? -g.z : g.x);
  im = rb ? (kb ? -g.y : g.w) : (kb ? g.w : g.y);
}

// ========== setup kernel: build the 6 group-matrix A-fragments once ==========
__global__ __launch_bounds__(BLK) void amat_kernel(
    const float* __restrict__ wts, uint4* __restrict__ Am) {
  __shared__ float4 gt4[24];
  const int t = threadIdx.x;
  if (t < 24) {
    const int l = 1 + t / 12, i = t % 12;
    const float a  = wts[(l * 12 + i) * 2 + 0] * 0.5f;
    const float bb = wts[(l * 12 + i) * 2 + 1] * 0.5f;
    float sa, ca, sb2, cb;
    sincosf(a, &sa, &ca);
    sincosf(bb, &sb2, &cb);
    gt4[t] = make_float4(cb * ca, sb2 * sa, sb2 * ca, -cb * sa);
  }
  __syncthreads();
  #pragma unroll
  for (int rep = 0; rep < 3; ++rep) {
    const int idx = t + rep * BLK;        // 0..767 = (pass, mat, lane)
    const int pass = idx >> 7;
    const int mat  = (idx >> 6) & 1;
    const int lw   = idx & 63;
    const int r    = lw & 15;
    const int ks   = lw >> 4;
    const int imf  = ks >> 1;             // k32 bit4 = im half
    const float4 g0 = gt4[pass * 4 + 0];  // acts on bit3
    const float4 g1 = gt4[pass * 4 + 1];  // bit2
    const float4 g2 = gt4[pass * 4 + 2];  // bit1
    const float4 g3 = gt4[pass * 4 + 3];  // bit0
    float b3r, b3i;
    gentry(g0, (r >> 3) & 1, ks & 1, b3r, b3i);   // k bit3 = ks bit0
    float t2r[2], t2i[2];
    #pragma unroll
    for (int k2 = 0; k2 < 2; ++k2) {
      float cr, ci;
      gentry(g1, (r >> 2) & 1, k2, cr, ci);
      t2r[k2] = b3r * cr - b3i * ci;
      t2i[k2] = b3r * ci + b3i * cr;
    }
    float t1r[4], t1i[4];
    #pragma unroll
    for (int k2 = 0; k2 < 2; ++k2)
      #pragma unroll
      for (int k1 = 0; k1 < 2; ++k1) {
        float cr, ci;
        gentry(g2, (r >> 1) & 1, k1, cr, ci);
        t1r[k2 * 2 + k1] = t2r[k2] * cr - t2i[k2] * ci;
        t1i[k2 * 2 + k1] = t2r[k2] * ci + t2i[k2] * cr;
      }
    float ev[8];
    #pragma unroll
    for (int j = 0; j < 8; ++j) {
      float cr, ci;
      gentry(g3, r & 1, j & 1, cr, ci);
      const int h2 = j >> 1;
      const float er = t1r[h2] * cr - t1i[h2] * ci;
      const float ei = t1r[h2] * ci + t1i[h2] * cr;
      ev[j] = (mat == 0) ? (imf ? -ei : er) : (imf ? er : ei);
    }
    unsigned u[4];
    #pragma unroll
    for (int q = 0; q < 4; ++q) {
      const h2v pk = __builtin_amdgcn_cvt_pkrtz(ev[2 * q], ev[2 * q + 1]);
      u[q] = __builtin_bit_cast(unsigned, pk);
    }
    Am[(pass * 2 + mat) * 64 + lw] = make_uint4(u[0], u[1], u[2], u[3]);
  }
}

// ================= main kernel: one sample per 256-thread block =================
__global__ __launch_bounds__(BLK, 4) void qsim_kernel(
    const float* __restrict__ sr, const float* __restrict__ si,
    const float* __restrict__ wts, const float* __restrict__ hw,
    const float* __restrict__ hb, const uint4* __restrict__ Am,
    float* __restrict__ out) {
  __shared__ __align__(16) unsigned sbuf[2][4096];  // 32 KB double-buffered
  float4* qv = (float4*)(sbuf[1]);   // dead before write_state touches sbuf[1]
  float* xacc = (float*)(sbuf[0]);   // used only after sbuf[0]'s last read

  const int t = threadIdx.x;
  const int lane = t & 63;
  const int w = t >> 6;                 // position bits 11..10
  const int s = blockIdx.x;

  // A-fragment loads (L2-resident 12 KB, coalesced b128)
  uint4 A1u[6], A2u[6];
  #pragma unroll
  for (int p = 0; p < 6; ++p) {
    A1u[p] = Am[(p * 2 + 0) * 64 + lane];
    A2u[p] = Am[(p * 2 + 1) * 64 + lane];
  }

  // Phase B: per-wire vectors q_i = G_layer0 * RY(a)RX(a)|0>
  if (t >= 64 && t < 76) {
    const int i = t - 64;
    const float ang = atan2f(si[(size_t)s * 4096 + i],
                             sr[(size_t)s * 4096 + i]) * 0.5f;
    float sn, cs;
    sincosf(ang, &sn, &cs);
    const float e0r = cs * cs, e0i = sn * sn, e1r = sn * cs, e1i = -sn * cs;
    const float a  = wts[i * 2 + 0] * 0.5f;
    const float bb = wts[i * 2 + 1] * 0.5f;
    float sa, ca, sb2, cb;
    sincosf(a, &sa, &ca);
    sincosf(bb, &sb2, &cb);
    const float g00r = cb * ca,  g00i = sb2 * sa, g01r = -sb2 * ca, g01i = -cb * sa;
    const float g10r = sb2 * ca, g10i = -cb * sa, g11r = cb * ca,   g11i = -sb2 * sa;
    const float q0r = g00r * e0r - g00i * e0i + g01r * e1r - g01i * e1i;
    const float q0i = g00r * e0i + g00i * e0r + g01r * e1i + g01i * e1r;
    const float q1r = g10r * e0r - g10i * e0i + g11r * e1r - g11i * e1i;
    const float q1i = g10r * e0i + g10i * e0r + g11r * e1i + g11i * e1r;
    qv[i] = make_float4(q0r, q0i, q1r, q1i);
  }
  __syncthreads();

  // Phase C: product state (F1 frame), written at B0(p), p=(w<<10)|(lane<<4)|l
  {
    const float4* q = qv;
    float Lr, Li;
    { const float4 q0 = q[0]; const int b0 = (w >> 1) & 1;
      Lr = b0 ? q0.z : q0.x; Li = b0 ? q0.w : q0.y; }
    { const float4 q1 = q[1]; const int b1 = w & 1;
      const float fr = b1 ? q1.z : q1.x, fi = b1 ? q1.w : q1.y;
      const float nr = Lr * fr - Li * fi, ni = Lr * fi + Li * fr;
      Lr = nr; Li = ni; }
    #pragma unroll
    for (int i = 2; i <= 7; ++i) {
      const float4 qq = q[i];
      const int bit = (lane >> (7 - i)) & 1;
      const float fr = bit ? qq.z : qq.x, fi = bit ? qq.w : qq.y;
      const float nr = Lr * fr - Li * fi, ni = Lr * fi + Li * fr;
      Lr = nr; Li = ni;
    }
    float LTr[4], LTi[4];
    { const float4 q8 = q[8], q9 = q[9];
      #pragma unroll
      for (int m = 0; m < 4; ++m) {
        const float xr2 = (m & 2) ? q8.z : q8.x, xi2 = (m & 2) ? q8.w : q8.y;
        const float yr = (m & 1) ? q9.z : q9.x, yi = (m & 1) ? q9.w : q9.y;
        const float tr = xr2 * yr - xi2 * yi, ti = xr2 * yi + xi2 * yr;
        LTr[m] = Lr * tr - Li * ti;
        LTi[m] = Lr * ti + Li * tr;
      } }
    float tbr[4], tbi[4];
    { const float4 qA = q[10], qB2 = q[11];
      #pragma unroll
      for (int m = 0; m < 4; ++m) {
        const float xr2 = (m & 2) ? qA.z : qA.x, xi2 = (m & 2) ? qA.w : qA.y;
        const float yr = (m & 1) ? qB2.z : qB2.x, yi = (m & 1) ? qB2.w : qB2.y;
        tbr[m] = xr2 * yr - xi2 * yi;
        tbi[m] = xr2 * yi + xi2 * yr;
      } }
    __syncthreads();                    // qv fully consumed
    // B0-mapped write base: lane bits 0..3 -> e4..e7, lane bits 4,5 -> e8,e9
    unsigned wb = 0u;
    #pragma unroll
    for (int k = 0; k < 4; ++k) wb ^= ((lane >> k) & 1) ? RT[0].wlb[k] : 0u;
    wb ^= (lane & 16) ? RT[0].wm[0] : 0u;
    wb ^= (lane & 32) ? RT[0].wm[1] : 0u;
    wb ^= (w & 1) ? RT[0].wwb[0] : 0u;
    wb ^= (w & 2) ? RT[0].wwb[1] : 0u;
    #pragma unroll
    for (int qq2 = 0; qq2 < 4; ++qq2) {
      uint4 v;
      unsigned* vp = &v.x;
      #pragma unroll
      for (int z = 0; z < 4; ++z) {
        const int l = qq2 * 4 + z;
        const float arl = LTr[l >> 2] * tbr[l & 3] - LTi[l >> 2] * tbi[l & 3];
        const float ail = LTr[l >> 2] * tbi[l & 3] + LTi[l >> 2] * tbr[l & 3];
        vp[z] = __builtin_bit_cast(unsigned, __builtin_amdgcn_cvt_pkrtz(arl, ail));
      }
      *(uint4*)(sbuf[0] + (wb ^ ((unsigned)qq2 << 2))) = v;
    }
  }
  __syncthreads();

  const unsigned sel = (lane & 32) ? 0x07060302u : 0x05040100u;
  f32x4 D1[4], D2[4];

  // double-buffered pass chain: one barrier per pass
  do_pass<0>(D1, D2, sbuf[0], A1u[0], A2u[0], lane, w, sel);
  write_state<1>(D1, D2, sbuf[1], lane, w);
  __syncthreads();
  do_pass<1>(D1, D2, sbuf[1], A1u[1], A2u[1], lane, w, sel);
  write_state<2>(D1, D2, sbuf[0], lane, w);
  __syncthreads();
  do_pass<2>(D1, D2, sbuf[0], A1u[2], A2u[2], lane, w, sel);
  write_state<3>(D1, D2, sbuf[1], lane, w);
  __syncthreads();
  do_pass<3>(D1, D2, sbuf[1], A1u[3], A2u[3], lane, w, sel);
  write_state<4>(D1, D2, sbuf[0], lane, w);
  __syncthreads();
  do_pass<4>(D1, D2, sbuf[0], A1u[4], A2u[4], lane, w, sel);
  write_state<5>(D1, D2, sbuf[1], lane, w);
  __syncthreads();
  do_pass<5>(D1, D2, sbuf[1], A1u[5], A2u[5], lane, w, sel);

  // measure: y = sum |amp|^2 * w(F4.A * p) + bias.  D layout: p =
  // (w<<10)|(m<<8)|((lane&15)<<4)|(((lane>>4)&3)<<2)|r
  const unsigned pbase = ((unsigned)w << 10) | ((unsigned)(lane & 15) << 4) |
                         ((unsigned)((lane >> 4) & 3) << 2);
  float hp[12];
  #pragma unroll
  for (int i = 0; i < 12; ++i) {
    const unsigned R = F4.A.r[11 - i];
    const float h = hw[i];
    hp[i] = (__popc(pbase & R & 0xCFCu) & 1) ? -h : h;
  }
  float c[16];
  #pragma unroll
  for (int v = 0; v < 16; ++v) c[v] = 0.f;
  #pragma unroll
  for (int i = 0; i < 12; ++i) {
    const unsigned R = F4.A.r[11 - i];
    const int mu = (int)((((R >> 8) & 3u) << 2) | (R & 3u));
    c[mu] += hp[i];
  }
  #pragma unroll
  for (int bb = 1; bb < 16; bb <<= 1)
    #pragma unroll
    for (int v = 0; v < 16; ++v)
      if (!(v & bb)) {
        const float x = c[v], y = c[v | bb];
        c[v] = x + y;
        c[v | bb] = x - y;
      }
  float acc = 0.f;
  #pragma unroll
  for (int m = 0; m < 4; ++m)
    #pragma unroll
    for (int r = 0; r < 4; ++r)
      acc += (D1[m][r] * D1[m][r] + D2[m][r] * D2[m][r]) * c[(m << 2) | r];
  #pragma unroll
  for (int off = 1; off < 64; off <<= 1) acc += __shfl_xor(acc, off, 64);

  __syncthreads();                      // sbuf[0] fully dead; reuse for xacc
  if (lane == 0) xacc[w] = acc;
  __syncthreads();
  if (t == 0) out[s] = xacc[0] + xacc[1] + xacc[2] + xacc[3] + hb[0];
}

extern "C" void kernel_launch(void* const* d_in, const int* in_sizes, int n_in,
                              void* d_out, int out_size, void* d_ws, size_t ws_size,
                              hipStream_t stream) {
  const float* sr  = (const float*)d_in[0];
  const float* si  = (const float*)d_in[1];
  const float* wts = (const float*)d_in[2];
  const float* hw  = (const float*)d_in[3];
  const float* hb  = (const float*)d_in[4];
  float* out = (float*)d_out;
  uint4* Am = (uint4*)d_ws;               // 768 * 16 B = 12 KB
  amat_kernel<<<1, BLK, 0, stream>>>(wts, Am);
  qsim_kernel<<<BATCH, BLK, 0, stream>>>(sr, si, wts, hw, hb, Am, out);
}

// Round 18
// 89.692 us; speedup vs baseline: 1.0836x; 1.0836x over previous
//
#include <hip/hip_runtime.h>

typedef __fp16 h2v __attribute__((ext_vector_type(2)));
typedef _Float16 f16x8 __attribute__((ext_vector_type(8)));
typedef float f32x4 __attribute__((ext_vector_type(4)));

#define BLK 256
#define BATCH 8192

// ================= GF(2) 12x12 compile-time machinery =================
struct M12 { unsigned r[12]; };

constexpr M12 mp_matrix() {
  // CNOT-ring permutation y = P x (verified rounds 1-17)
  M12 m{};
  for (int p = 0; p <= 10; ++p) m.r[p] = (0xFFFu >> p) << p;
  m.r[11] = 0x7FFu;
  return m;
}
constexpr M12 MP = mp_matrix();

constexpr unsigned mv(const M12 m, unsigned v) {
  unsigned y = 0;
  for (int p = 0; p < 12; ++p)
    y |= (unsigned)(__builtin_popcount(m.r[p] & v) & 1) << p;
  return y;
}
constexpr M12 mmul(const M12 a, const M12 b) {     // c(x) = a(b(x))
  M12 c{};
  for (int p = 0; p < 12; ++p) {
    unsigned acc = 0;
    for (int q = 0; q < 12; ++q)
      if ((a.r[p] >> q) & 1u) acc ^= b.r[q];
    c.r[p] = acc;
  }
  return c;
}
constexpr M12 minv(const M12 a0) {
  unsigned a[12] = {}, v[12] = {};
  for (int i = 0; i < 12; ++i) { a[i] = a0.r[i]; v[i] = 1u << i; }
  for (int c = 0; c < 12; ++c) {
    int piv = c;
    while (!((a[piv] >> c) & 1u)) ++piv;   // OOB => constexpr error (singular)
    unsigned ta = a[piv], tv = v[piv];
    a[piv] = a[c]; v[piv] = v[c]; a[c] = ta; v[c] = tv;
    for (int r2 = 0; r2 < 12; ++r2)
      if (r2 != c && ((a[r2] >> c) & 1u)) { a[r2] ^= a[c]; v[r2] ^= v[c]; }
  }
  M12 out{};
  for (int i = 0; i < 12; ++i) out.r[i] = v[i];
  return out;
}
constexpr unsigned colq(const M12 m, int q) {
  unsigned c = 0;
  for (int p = 0; p < 12; ++p) c |= ((m.r[p] >> q) & 1u) << p;
  return c;
}
constexpr M12 from_cols(const unsigned (&c)[12]) {
  M12 m{};
  for (int p = 0; p < 12; ++p) {
    unsigned row = 0;
    for (int j = 0; j < 12; ++j) row |= ((c[j] >> p) & 1u) << j;
    m.r[p] = row;
  }
  return m;
}
constexpr M12 mk_id() { M12 m{}; for (int p = 0; p < 12; ++p) m.r[p] = 1u << p; return m; }
constexpr M12 MID = mk_id();
constexpr M12 MPI = minv(MP);

constexpr bool meq(const M12 a, const M12 b) {
  for (int p = 0; p < 12; ++p) if (a.r[p] != b.r[p]) return false;
  return true;
}
static_assert(meq(mmul(MP, MPI), MID), "P inverse");

struct Frame { M12 A, Ai; };
constexpr Frame FID{MID, MID};
constexpr Frame absorb(const Frame f) { return Frame{ mmul(MP, f.A), mmul(f.Ai, MPI) }; }
constexpr Frame apply_tau(const Frame f, const M12 t) {
  return Frame{ mmul(f.A, minv(t)), mmul(t, f.Ai) };
}

// ---- completion search (sources + null-space completion) ----
struct SSet { unsigned S[12]; };

constexpr int rank_msk(const unsigned* v, int n, unsigned msk) {
  unsigned basis[5] = {};
  int r = 0;
  for (int i = 0; i < n; ++i) {
    unsigned x = v[i] & msk;
    for (int b = 4; b >= 0; --b) {
      if (!((x >> b) & 1u)) continue;
      if (basis[b]) x ^= basis[b];
      else { basis[b] = x; ++r; break; }
    }
  }
  return r;
}
constexpr bool ins_ech(unsigned (&e)[12], unsigned x) {
  for (int b = 11; b >= 0; --b) {
    if (!((x >> b) & 1u)) continue;
    if (e[b]) x ^= e[b];
    else { e[b] = x; return true; }
  }
  return false;
}
// Greedy: S[4..7] maximize bank-bit [1:0] diversity first (B swizzle can
// inject [4:2] later), then overall bank rank [4:0].
constexpr SSet build_S(const Frame f, const int* qs) {
  SSet s{};
  unsigned rows[4] = {};
  for (int i = 0; i < 4; ++i) {
    s.S[i] = colq(f.Ai, qs[i]);
    rows[i] = f.A.r[qs[i]];
  }
  unsigned R[4] = {rows[0], rows[1], rows[2], rows[3]};
  int pivcol[4] = {-1, -1, -1, -1};
  int nr = 0;
  for (int cc = 0; cc < 12 && nr < 4; ++cc) {
    int pr = -1;
    for (int r2 = nr; r2 < 4; ++r2) if ((R[r2] >> cc) & 1u) { pr = r2; break; }
    if (pr < 0) continue;
    unsigned tmp = R[nr]; R[nr] = R[pr]; R[pr] = tmp;
    for (int r2 = 0; r2 < 4; ++r2)
      if (r2 != nr && ((R[r2] >> cc) & 1u)) R[r2] ^= R[nr];
    pivcol[nr] = cc; ++nr;
  }
  unsigned nb[8] = {};
  int nc = 0;
  for (int j = 0; j < 12; ++j) {
    bool isp = false;
    for (int k = 0; k < nr; ++k) if (pivcol[k] == j) isp = true;
    if (isp) continue;
    unsigned v = 1u << j;
    for (int k = 0; k < nr; ++k) if ((R[k] >> j) & 1u) v |= 1u << pivcol[k];
    nb[nc] = v;
    ++nc;
  }
  unsigned pool[36] = {};
  int np = 0;
  for (int j = 0; j < 8; ++j) pool[np++] = nb[j];
  for (int j = 0; j < 8; ++j)
    for (int k = j + 1; k < 8; ++k) pool[np++] = nb[j] ^ nb[k];
  unsigned ech[12] = {};
  unsigned readset[5] = {};
  int nrs = 0;
  readset[nrs++] = s.S[0];
  for (int slot = 4; slot <= 7; ++slot) {
    int best = -1;
    unsigned bestc = 0;
    for (int c = 0; c < np; ++c) {
      unsigned tmp[12];
      for (int z = 0; z < 12; ++z) tmp[z] = ech[z];
      if (!ins_ech(tmp, pool[c])) continue;
      readset[nrs] = pool[c];
      const int score = rank_msk(readset, nrs + 1, 3u) * 8 +
                        rank_msk(readset, nrs + 1, 31u);
      if (score > best) { best = score; bestc = pool[c]; }
    }
    s.S[slot] = bestc;
    ins_ech(ech, bestc);
    readset[nrs++] = bestc;
  }
  const int rem[4] = {8, 9, 10, 11};
  for (int t = 0; t < 4; ++t) {
    for (int c = 0; c < np; ++c) {
      unsigned tmp[12];
      for (int z = 0; z < 12; ++z) tmp[z] = ech[z];
      if (!ins_ech(tmp, pool[c])) continue;
      s.S[rem[t]] = pool[c];
      ins_ech(ech, pool[c]);
      break;
    }
  }
  return s;
}
constexpr unsigned T4[4] = {8u, 4u, 2u, 1u};
constexpr M12 tau_of(const SSet s) {
  unsigned Sc[12], Dc[12];
  for (int i = 0; i < 12; ++i) {
    Sc[i] = s.S[i];
    Dc[i] = (i < 4) ? T4[i] : (1u << i);
  }
  return mmul(from_cols(Dc), minv(from_cols(Sc)));
}
constexpr bool chk_group(const Frame f, const int* qs) {
  for (int i = 0; i < 4; ++i) if (colq(f.Ai, qs[i]) != T4[i]) return false;
  return true;
}

// ---- B swizzle: layout bijection keyed on addr bits [11:5], injecting into
// bank bits [4:2]; identity on [1:0] keeps b128 blocks intact.  Linear.
struct BSw { unsigned mk[7]; };
constexpr unsigned bapp(const BSw& b, unsigned v) {
  unsigned o = v;
  for (int k = 0; k < 7; ++k)
    if ((v >> (5 + k)) & 1u) o ^= b.mk[k];
  return o;
}
constexpr int brank_read(const BSw& b, const SSet& s) {
  unsigned v[5] = { bapp(b, s.S[0]), bapp(b, s.S[4]), bapp(b, s.S[5]),
                    bapp(b, s.S[6]), bapp(b, s.S[7]) };
  return rank_msk(v, 5, 31u);
}
constexpr BSw find_B(const SSet& s) {
  BSw b{};
  int best = brank_read(b, s);
  for (int sw = 0; sw < 3; ++sw)
    for (int k = 0; k < 7; ++k) {
      unsigned bv = b.mk[k];
      for (unsigned v = 0; v < 8; ++v) {
        b.mk[k] = v << 2;
        const int r = brank_read(b, s);
        if (r > best) { best = r; bv = v << 2; }
      }
      b.mk[k] = bv;
    }
  return b;
}

constexpr int QA[4] = {11, 10, 9, 8};
constexpr int QB[4] = {7, 6, 5, 4};
constexpr int QC[4] = {3, 2, 1, 0};

constexpr Frame F1  = absorb(FID);
constexpr SSet C0 = build_S(F1, QA);
constexpr M12  T0 = tau_of(C0);
constexpr Frame F2a = apply_tau(F1, T0);
constexpr SSet C1 = build_S(F2a, QB);
constexpr M12  T1 = tau_of(C1);
constexpr Frame F2b = apply_tau(F2a, T1);
constexpr SSet C2 = build_S(F2b, QC);
constexpr M12  T2 = tau_of(C2);
constexpr Frame F2c = apply_tau(F2b, T2);
constexpr Frame F3  = absorb(F2c);
constexpr SSet C3 = build_S(F3, QA);
constexpr M12  T3m = tau_of(C3);
constexpr Frame F3a = apply_tau(F3, T3m);
constexpr SSet C4 = build_S(F3a, QB);
constexpr M12  T4m = tau_of(C4);
constexpr Frame F3b = apply_tau(F3a, T4m);
constexpr SSet C5 = build_S(F3b, QC);
constexpr M12  T5m = tau_of(C5);
constexpr Frame F3c = apply_tau(F3b, T5m);
constexpr Frame F4  = absorb(F3c);

static_assert(chk_group(F2a, QA), "G2a");
static_assert(chk_group(F2b, QB), "G2b");
static_assert(chk_group(F2c, QC), "G2c");
static_assert(chk_group(F3a, QA), "G3a");
static_assert(chk_group(F3b, QB), "G3b");
static_assert(chk_group(F3c, QC), "G3c");
static_assert(F2a.A.r[11] == 8u && F2a.A.r[10] == 4u && F2a.A.r[9] == 2u && F2a.A.r[8] == 1u, "rows2a");
static_assert(F2b.A.r[7]  == 8u && F2b.A.r[6]  == 4u && F2b.A.r[5] == 2u && F2b.A.r[4] == 1u, "rows2b");
static_assert(F2c.A.r[3]  == 8u && F2c.A.r[2]  == 4u && F2c.A.r[1] == 2u && F2c.A.r[0] == 1u, "rows2c");
static_assert(F3a.A.r[11] == 8u && F3a.A.r[10] == 4u && F3a.A.r[9] == 2u && F3a.A.r[8] == 1u, "rows3a");
static_assert(F3b.A.r[7]  == 8u && F3b.A.r[6]  == 4u && F3b.A.r[5] == 2u && F3b.A.r[4] == 1u, "rows3b");
static_assert(F3c.A.r[3]  == 8u && F3c.A.r[2]  == 4u && F3c.A.r[1] == 2u && F3c.A.r[0] == 1u, "rows3c");

constexpr BSw B0 = find_B(C0);
constexpr BSw B1 = find_B(C1);
constexpr BSw B2 = find_B(C2);
constexpr BSw B3 = find_B(C3);
constexpr BSw B4 = find_B(C4);
constexpr BSw B5 = find_B(C5);
static_assert(brank_read(B0, C0) >= 3 && brank_read(B1, C1) >= 3 &&
              brank_read(B2, C2) >= 3 && brank_read(B3, C3) >= 3 &&
              brank_read(B4, C4) >= 3 && brank_read(B5, C5) >= 3, "rr");

// per-pass tables: read side (reads scatter via B(tau^-1)), write side
// (linear D-positions mapped through the same B)
struct PT {
  unsigned rlb[5]; unsigned rwb[2]; unsigned ro[32];
  unsigned wlb[4]; unsigned wm[2]; unsigned wwb[2];
};
constexpr PT mk_pt(const SSet s, const BSw b) {
  PT t{};
  t.rlb[0] = bapp(b, s.S[4]); t.rlb[1] = bapp(b, s.S[5]);
  t.rlb[2] = bapp(b, s.S[6]); t.rlb[3] = bapp(b, s.S[7]);
  t.rlb[4] = bapp(b, s.S[0]);
  t.rwb[0] = bapp(b, s.S[10]); t.rwb[1] = bapp(b, s.S[11]);
  for (int m = 0; m < 4; ++m)
    for (int j = 0; j < 8; ++j)
      t.ro[(m << 3) | j] = bapp(b,
          ((m & 1) ? s.S[8] : 0u) ^ ((m & 2) ? s.S[9] : 0u) ^
          ((j & 1) ? s.S[3] : 0u) ^ ((j & 2) ? s.S[2] : 0u) ^
          ((j & 4) ? s.S[1] : 0u));
  for (int k = 0; k < 4; ++k) t.wlb[k] = bapp(b, 1u << (4 + k));
  t.wm[0] = bapp(b, 256u);  t.wm[1] = bapp(b, 512u);
  t.wwb[0] = bapp(b, 1024u); t.wwb[1] = bapp(b, 2048u);
  return t;
}
constexpr PT RT[6] = { mk_pt(C0, B0), mk_pt(C1, B1), mk_pt(C2, B2),
                       mk_pt(C3, B3), mk_pt(C4, B4), mk_pt(C5, B5) };

// ================= device helpers =================
template<int PI>
__device__ __forceinline__ unsigned rbase_of(const int lane, const int w) {
  unsigned rb = 0u;
  #pragma unroll
  for (int k = 0; k < 4; ++k) rb ^= ((lane >> k) & 1) ? RT[PI].rlb[k] : 0u;
  rb ^= ((lane >> 4) & 1) ? RT[PI].rlb[4] : 0u;
  rb ^= (w & 1) ? RT[PI].rwb[0] : 0u;
  rb ^= (w & 2) ? RT[PI].rwb[1] : 0u;
  return rb;
}

// scatter-read B-fragments (half-wave partners read identical addresses ->
// LDS broadcast; sel extracts re/im plane) + MFMAs
template<int PI>
__device__ __forceinline__ void do_pass(f32x4 (&D1)[4], f32x4 (&D2)[4],
                                        const unsigned* sb,
                                        const uint4 a1u, const uint4 a2u,
                                        const int lane, const int w,
                                        const unsigned sel) {
  const f16x8 A1f = __builtin_bit_cast(f16x8, a1u);
  const f16x8 A2f = __builtin_bit_cast(f16x8, a2u);
  const unsigned rb = rbase_of<PI>(lane, w);
  const f32x4 z4 = {0.f, 0.f, 0.f, 0.f};
  #pragma unroll
  for (int m = 0; m < 4; ++m) {
    unsigned amp[8];
    #pragma unroll
    for (int j = 0; j < 8; ++j)
      amp[j] = sb[rb ^ RT[PI].ro[(m << 3) | j]];
    uint4 bw;
    bw.x = __builtin_amdgcn_perm(amp[1], amp[0], sel);
    bw.y = __builtin_amdgcn_perm(amp[3], amp[2], sel);
    bw.z = __builtin_amdgcn_perm(amp[5], amp[4], sel);
    bw.w = __builtin_amdgcn_perm(amp[7], amp[6], sel);
    const f16x8 Bf = __builtin_bit_cast(f16x8, bw);
    D1[m] = __builtin_amdgcn_mfma_f32_16x16x32_f16(A1f, Bf, z4, 0, 0, 0);
    D2[m] = __builtin_amdgcn_mfma_f32_16x16x32_f16(A2f, Bf, z4, 0, 0, 0);
  }
}

// b128 write of D-layout state at B(own position); PI = pass that READS this
// buffer (so writer and reader share the same B layout).
template<int PI>
__device__ __forceinline__ void write_state(const f32x4 (&D1)[4],
                                            const f32x4 (&D2)[4],
                                            unsigned* sb, const int lane,
                                            const int w) {
  unsigned wb = (unsigned)((lane >> 4) << 2);   // ks bits e2,e3 (B-identity)
  #pragma unroll
  for (int k = 0; k < 4; ++k) wb ^= ((lane >> k) & 1) ? RT[PI].wlb[k] : 0u;
  wb ^= (w & 1) ? RT[PI].wwb[0] : 0u;
  wb ^= (w & 2) ? RT[PI].wwb[1] : 0u;
  #pragma unroll
  for (int m = 0; m < 4; ++m) {
    const unsigned addr = wb ^ ((m & 1) ? RT[PI].wm[0] : 0u)
                             ^ ((m & 2) ? RT[PI].wm[1] : 0u);
    uint4 v;
    v.x = __builtin_bit_cast(unsigned, __builtin_amdgcn_cvt_pkrtz(D1[m][0], D2[m][0]));
    v.y = __builtin_bit_cast(unsigned, __builtin_amdgcn_cvt_pkrtz(D1[m][1], D2[m][1]));
    v.z = __builtin_bit_cast(unsigned, __builtin_amdgcn_cvt_pkrtz(D1[m][2], D2[m][2]));
    v.w = __builtin_bit_cast(unsigned, __builtin_amdgcn_cvt_pkrtz(D1[m][3], D2[m][3]));
    *(uint4*)(sb + addr) = v;
  }
}

// gate entry G=[[(gr,gi),(-hr,hi)],[(hr,hi),(gr,-gi)]], g=(gr,gi,hr,hi)
__device__ __forceinline__ void gentry(const float4 g, const int rb,
                                       const int kb, float& re, float& im) {
  re = rb ? (kb ? g.x : g.z) : (kb ? -g.z : g.x);
  im = rb ? (kb ? -g.y : g.w) : (kb ? g.w : g.y);
}

// ========== setup kernel: build the 6 group-matrix A-fragments once ==========
__global__ __launch_bounds__(BLK) void amat_kernel(
    const float* __restrict__ wts, uint4* __restrict__ Am) {
  __shared__ float4 gt4[24];
  const int t = threadIdx.x;
  if (t < 24) {
    const int l = 1 + t / 12, i = t % 12;
    const float a  = wts[(l * 12 + i) * 2 + 0] * 0.5f;
    const float bb = wts[(l * 12 + i) * 2 + 1] * 0.5f;
    float sa, ca, sb2, cb;
    sincosf(a, &sa, &ca);
    sincosf(bb, &sb2, &cb);
    gt4[t] = make_float4(cb * ca, sb2 * sa, sb2 * ca, -cb * sa);
  }
  __syncthreads();
  #pragma unroll
  for (int rep = 0; rep < 3; ++rep) {
    const int idx = t + rep * BLK;        // 0..767 = (pass, mat, lane)
    const int pass = idx >> 7;
    const int mat  = (idx >> 6) & 1;
    const int lw   = idx & 63;
    const int r    = lw & 15;
    const int ks   = lw >> 4;
    const int imf  = ks >> 1;             // k32 bit4 = im half
    const float4 g0 = gt4[pass * 4 + 0];  // acts on bit3
    const float4 g1 = gt4[pass * 4 + 1];  // bit2
    const float4 g2 = gt4[pass * 4 + 2];  // bit1
    const float4 g3 = gt4[pass * 4 + 3];  // bit0
    float b3r, b3i;
    gentry(g0, (r >> 3) & 1, ks & 1, b3r, b3i);   // k bit3 = ks bit0
    float t2r[2], t2i[2];
    #pragma unroll
    for (int k2 = 0; k2 < 2; ++k2) {
      float cr, ci;
      gentry(g1, (r >> 2) & 1, k2, cr, ci);
      t2r[k2] = b3r * cr - b3i * ci;
      t2i[k2] = b3r * ci + b3i * cr;
    }
    float t1r[4], t1i[4];
    #pragma unroll
    for (int k2 = 0; k2 < 2; ++k2)
      #pragma unroll
      for (int k1 = 0; k1 < 2; ++k1) {
        float cr, ci;
        gentry(g2, (r >> 1) & 1, k1, cr, ci);
        t1r[k2 * 2 + k1] = t2r[k2] * cr - t2i[k2] * ci;
        t1i[k2 * 2 + k1] = t2r[k2] * ci + t2i[k2] * cr;
      }
    float ev[8];
    #pragma unroll
    for (int j = 0; j < 8; ++j) {
      float cr, ci;
      gentry(g3, r & 1, j & 1, cr, ci);
      const int h2 = j >> 1;
      const float er = t1r[h2] * cr - t1i[h2] * ci;
      const float ei = t1r[h2] * ci + t1i[h2] * cr;
      ev[j] = (mat == 0) ? (imf ? -ei : er) : (imf ? er : ei);
    }
    unsigned u[4];
    #pragma unroll
    for (int q = 0; q < 4; ++q) {
      const h2v pk = __builtin_amdgcn_cvt_pkrtz(ev[2 * q], ev[2 * q + 1]);
      u[q] = __builtin_bit_cast(unsigned, pk);
    }
    Am[(pass * 2 + mat) * 64 + lw] = make_uint4(u[0], u[1], u[2], u[3]);
  }
}

// ================= main kernel: one sample per 256-thread block =================
__global__ __launch_bounds__(BLK, 4) void qsim_kernel(
    const float* __restrict__ sr, const float* __restrict__ si,
    const float* __restrict__ wts, const float* __restrict__ hw,
    const float* __restrict__ hb, const uint4* __restrict__ Am,
    float* __restrict__ out) {
  __shared__ __align__(16) unsigned sbuf[2][4096];  // 32 KB double-buffered
  float4* qv = (float4*)(sbuf[1]);   // dead before write_state touches sbuf[1]
  float* xacc = (float*)(sbuf[0]);   // used only after sbuf[0]'s last read

  const int t = threadIdx.x;
  const int lane = t & 63;
  const int w = t >> 6;                 // position bits 11..10
  const int s = blockIdx.x;

  // A-fragment loads (L2-resident 12 KB, coalesced b128)
  uint4 A1u[6], A2u[6];
  #pragma unroll
  for (int p = 0; p < 6; ++p) {
    A1u[p] = Am[(p * 2 + 0) * 64 + lane];
    A2u[p] = Am[(p * 2 + 1) * 64 + lane];
  }

  // Phase B: per-wire vectors q_i = G_layer0 * RY(a)RX(a)|0>
  if (t >= 64 && t < 76) {
    const int i = t - 64;
    const float ang = atan2f(si[(size_t)s * 4096 + i],
                             sr[(size_t)s * 4096 + i]) * 0.5f;
    float sn, cs;
    sincosf(ang, &sn, &cs);
    const float e0r = cs * cs, e0i = sn * sn, e1r = sn * cs, e1i = -sn * cs;
    const float a  = wts[i * 2 + 0] * 0.5f;
    const float bb = wts[i * 2 + 1] * 0.5f;
    float sa, ca, sb2, cb;
    sincosf(a, &sa, &ca);
    sincosf(bb, &sb2, &cb);
    const float g00r = cb * ca,  g00i = sb2 * sa, g01r = -sb2 * ca, g01i = -cb * sa;
    const float g10r = sb2 * ca, g10i = -cb * sa, g11r = cb * ca,   g11i = -sb2 * sa;
    const float q0r = g00r * e0r - g00i * e0i + g01r * e1r - g01i * e1i;
    const float q0i = g00r * e0i + g00i * e0r + g01r * e1i + g01i * e1r;
    const float q1r = g10r * e0r - g10i * e0i + g11r * e1r - g11i * e1i;
    const float q1i = g10r * e0i + g10i * e0r + g11r * e1i + g11i * e1r;
    qv[i] = make_float4(q0r, q0i, q1r, q1i);
  }
  __syncthreads();

  // Phase C: product state (F1 frame), written at B0(p), p=(w<<10)|(lane<<4)|l
  {
    const float4* q = qv;
    float Lr, Li;
    { const float4 q0 = q[0]; const int b0 = (w >> 1) & 1;
      Lr = b0 ? q0.z : q0.x; Li = b0 ? q0.w : q0.y; }
    { const float4 q1 = q[1]; const int b1 = w & 1;
      const float fr = b1 ? q1.z : q1.x, fi = b1 ? q1.w : q1.y;
      const float nr = Lr * fr - Li * fi, ni = Lr * fi + Li * fr;
      Lr = nr; Li = ni; }
    #pragma unroll
    for (int i = 2; i <= 7; ++i) {
      const float4 qq = q[i];
      const int bit = (lane >> (7 - i)) & 1;
      const float fr = bit ? qq.z : qq.x, fi = bit ? qq.w : qq.y;
      const float nr = Lr * fr - Li * fi, ni = Lr * fi + Li * fr;
      Lr = nr; Li = ni;
    }
    float LTr[4], LTi[4];
    { const float4 q8 = q[8], q9 = q[9];
      #pragma unroll
      for (int m = 0; m < 4; ++m) {
        const float xr2 = (m & 2) ? q8.z : q8.x, xi2 = (m & 2) ? q8.w : q8.y;
        const float yr = (m & 1) ? q9.z : q9.x, yi = (m & 1) ? q9.w : q9.y;
        const float tr = xr2 * yr - xi2 * yi, ti = xr2 * yi + xi2 * yr;
        LTr[m] = Lr * tr - Li * ti;
        LTi[m] = Lr * ti + Li * tr;
      } }
    float tbr[4], tbi[4];
    { const float4 qA = q[10], qB2 = q[11];
      #pragma unroll
      for (int m = 0; m < 4; ++m) {
        const float xr2 = (m & 2) ? qA.z : qA.x, xi2 = (m & 2) ? qA.w : qA.y;
        const float yr = (m & 1) ? qB2.z : qB2.x, yi = (m & 1) ? qB2.w : qB2.y;
        tbr[m] = xr2 * yr - xi2 * yi;
        tbi[m] = xr2 * yi + xi2 * yr;
      } }
    __syncthreads();                    // qv fully consumed
    // B0-mapped write base: lane bits 0..3 -> e4..e7, lane bits 4,5 -> e8,e9
    unsigned wb = 0u;
    #pragma unroll
    for (int k = 0; k < 4; ++k) wb ^= ((lane >> k) & 1) ? RT[0].wlb[k] : 0u;
    wb ^= (lane & 16) ? RT[0].wm[0] : 0u;
    wb ^= (lane & 32) ? RT[0].wm[1] : 0u;
    wb ^= (w & 1) ? RT[0].wwb[0] : 0u;
    wb ^= (w & 2) ? RT[0].wwb[1] : 0u;
    #pragma unroll
    for (int qq2 = 0; qq2 < 4; ++qq2) {
      uint4 v;
      unsigned* vp = &v.x;
      #pragma unroll
      for (int z = 0; z < 4; ++z) {
        const int l = qq2 * 4 + z;
        const float arl = LTr[l >> 2] * tbr[l & 3] - LTi[l >> 2] * tbi[l & 3];
        const float ail = LTr[l >> 2] * tbi[l & 3] + LTi[l >> 2] * tbr[l & 3];
        vp[z] = __builtin_bit_cast(unsigned, __builtin_amdgcn_cvt_pkrtz(arl, ail));
      }
      *(uint4*)(sbuf[0] + (wb ^ ((unsigned)qq2 << 2))) = v;
    }
  }
  __syncthreads();

  const unsigned sel = (lane & 32) ? 0x07060302u : 0x05040100u;
  f32x4 D1[4], D2[4];

  // double-buffered pass chain: one barrier per pass
  do_pass<0>(D1, D2, sbuf[0], A1u[0], A2u[0], lane, w, sel);
  write_state<1>(D1, D2, sbuf[1], lane, w);
  __syncthreads();
  do_pass<1>(D1, D2, sbuf[1], A1u[1], A2u[1], lane, w, sel);
  write_state<2>(D1, D2, sbuf[0], lane, w);
  __syncthreads();
  do_pass<2>(D1, D2, sbuf[0], A1u[2], A2u[2], lane, w, sel);
  write_state<3>(D1, D2, sbuf[1], lane, w);
  __syncthreads();
  do_pass<3>(D1, D2, sbuf[1], A1u[3], A2u[3], lane, w, sel);
  write_state<4>(D1, D2, sbuf[0], lane, w);
  __syncthreads();
  do_pass<4>(D1, D2, sbuf[0], A1u[4], A2u[4], lane, w, sel);
  write_state<5>(D1, D2, sbuf[1], lane, w);
  __syncthreads();
  do_pass<5>(D1, D2, sbuf[1], A1u[5], A2u[5], lane, w, sel);

  // measure: y = sum |amp|^2 * w(F4.A * p) + bias.  D layout: p =
  // (w<<10)|(m<<8)|((lane&15)<<4)|(((lane>>4)&3)<<2)|r
  const unsigned pbase = ((unsigned)w << 10) | ((unsigned)(lane & 15) << 4) |
                         ((unsigned)((lane >> 4) & 3) << 2);
  float hp[12];
  #pragma unroll
  for (int i = 0; i < 12; ++i) {
    const unsigned R = F4.A.r[11 - i];
    const float h = hw[i];
    hp[i] = (__popc(pbase & R & 0xCFCu) & 1) ? -h : h;
  }
  float c[16];
  #pragma unroll
  for (int v = 0; v < 16; ++v) c[v] = 0.f;
  #pragma unroll
  for (int i = 0; i < 12; ++i) {
    const unsigned R = F4.A.r[11 - i];
    const int mu = (int)((((R >> 8) & 3u) << 2) | (R & 3u));
    c[mu] += hp[i];
  }
  #pragma unroll
  for (int bb = 1; bb < 16; bb <<= 1)
    #pragma unroll
    for (int v = 0; v < 16; ++v)
      if (!(v & bb)) {
        const float x = c[v], y = c[v | bb];
        c[v] = x + y;
        c[v | bb] = x - y;
      }
  float acc = 0.f;
  #pragma unroll
  for (int m = 0; m < 4; ++m)
    #pragma unroll
    for (int r = 0; r < 4; ++r)
      acc += (D1[m][r] * D1[m][r] + D2[m][r] * D2[m][r]) * c[(m << 2) | r];
  #pragma unroll
  for (int off = 1; off < 64; off <<= 1) acc += __shfl_xor(acc, off, 64);

  __syncthreads();                      // sbuf[0] fully dead; reuse for xacc
  if (lane == 0) xacc[w] = acc;
  __syncthreads();
  if (t == 0) out[s] = xacc[0] + xacc[1] + xacc[2] + xacc[3] + hb[0];
}

extern "C" void kernel_launch(void* const* d_in, const int* in_sizes, int n_in,
                              void* d_out, int out_size, void* d_ws, size_t ws_size,
                              hipStream_t stream) {
  const float* sr  = (const float*)d_in[0];
  const float* si  = (const float*)d_in[1];
  const float* wts = (const float*)d_in[2];
  const float* hw  = (const float*)d_in[3];
  const float* hb  = (const float*)d_in[4];
  float* out = (float*)d_out;
  uint4* Am = (uint4*)d_ws;               // 768 * 16 B = 12 KB
  amat_kernel<<<1, BLK, 0, stream>>>(wts, Am);
  qsim_kernel<<<BATCH, BLK, 0, stream>>>(sr, si, wts, hw, hb, Am, out);
}